// Round 12
// baseline (275.992 us; speedup 1.0000x reference)
//
#include <hip/hip_runtime.h>

// LSTM B=4096, S=512, INPUT=1, HIDDEN=20 + linear head.
// R11b: R11 with the compile fix (STEP returns y; float& cannot bind to an
// ext_vector element).  Semantics identical to R11:
//  BUG FIX (R10 absmax 0.0859): head MFMA now runs on the NEW h (bf rebuilt
//  after activations): y(t) = W_lin.h(t) + b_lin, stored unskewed.
//  PRECISION FIX: x*W_ih + bias enter via the MFMA's f32 C-operand (20
//  fmaf/step from f32 constants) -> error sources identical to R6b (h f16,
//  W_hh f16, f32 accum), which passed at 9.77e-4.
// Design: every LDS-ring variant (R3-R9) walled at ~850-1000 cyc/step ->
// latency-bound on h(t-1)->gates->c->h(t).  One wave carries 16 chains;
// 5 mfma_f32_16x16x32_f16 compute all 80x16 gate pre-acts + 1 head mfma.
// No LDS, no barriers: the MFMA does the h broadcast/reduction.
//  - A-row perm: mfma m's row 4Q+r = gate r of unit 5Q+m -> lane (q,n)'s C
//    regs = [i,f,g,o] of unit 5q+m, chain n = the units whose c it owns.
//    (C layout col=lane&15, row=4*(lane>>4)+reg: HW-verified m89.)
//  - k-slots: lane (q,n) slot s = unit 5q+s (s<5), 0 otherwise; same
//    convention on A and B (consistent k-permutation cancels).
//  - Head: A row 0 = W_lin (f16); b_lin via C-input; y -> lanes 0-15 reg 0.
//  - x: f32 in VGPRs, double-buffered across 8-step bodies.
// Activations: fused-reciprocal (5 exp2 + 2 rcp per unit), c >= -34.
// Grid: 256 blocks x 64 threads = 1 wave/CU, 16 chains each.

#define BATCH 4096
#define SLEN  512
#define H     20
#define LOG2E 1.44269504088896340736f

typedef _Float16 f16x8 __attribute__((ext_vector_type(8)));
typedef float    f32x4 __attribute__((ext_vector_type(4)));

__device__ __forceinline__ float fexp2(float x) { return __builtin_amdgcn_exp2f(x); }
__device__ __forceinline__ float frcp(float x)  { return __builtin_amdgcn_rcpf(x); }

__global__ __launch_bounds__(64, 1) void lstm_fused(
    const float* __restrict__ x,      // [B, S, 1]
    const float* __restrict__ W_ih,   // [80, 1]
    const float* __restrict__ W_hh,   // [80, 20]
    const float* __restrict__ b_ih,   // [80]
    const float* __restrict__ b_hh,   // [80]
    const float* __restrict__ W_lin,  // [1, 20]
    const float* __restrict__ b_lin,  // [1]
    float* __restrict__ out)          // [B, S, 1]
{
    const int lane = threadIdx.x;      // 0..63
    const int q    = lane >> 4;        // k-group / unit-block 0..3
    const int n    = lane & 15;        // chain column 0..15
    const long b   = (long)blockIdx.x * 16 + n;   // 256*16 = 4096 exact

    const float s1 = -LOG2E;           // sigmoid pre-scale
    const float s2 = -2.0f * LOG2E;    // tanh pre-scale

    // ---- A fragments (f16, constant).  Lane's A-row = n, k-slots by q. ----
    // mfma m row 4Q+r = gate r of unit 5Q+m;  k-slot s (s<5) = unit 5q+s.
    const int gA  = n & 3;              // gate carried by this lane's A-row
    const int uA  = (n >> 2) * 5;       // unit-block base of this lane's A-row
    const float scA = (gA == 2) ? s2 : s1;   // torch gate order i,f,g,o
    f16x8 am[5];
#pragma unroll
    for (int m = 0; m < 5; ++m) {
        const int row = gA * H + uA + m;
#pragma unroll
        for (int s = 0; s < 8; ++s) {
            const float v = (s < 5) ? scA * W_hh[row * H + 5 * q + s] : 0.0f;
            am[m][s] = (_Float16)v;
        }
    }
    f16x8 ah;
#pragma unroll
    for (int s = 0; s < 8; ++s) {
        const float v = (n == 0 && s < 5) ? W_lin[5 * q + s] : 0.0f;
        ah[s] = (_Float16)v;
    }

    // ---- f32 C-init constants: lane (q,n) C position (m, r) = gate r of
    // unit 5q+m, chain n -> init = sc_r*(x_n*W_ih + b_ih + b_hh). ----
    float xw[5][4], bb[5][4];
#pragma unroll
    for (int m = 0; m < 5; ++m)
#pragma unroll
        for (int r = 0; r < 4; ++r) {
            const float sc = (r == 2) ? s2 : s1;
            const int row = r * H + 5 * q + m;
            xw[m][r] = sc * W_ih[row];
            bb[m][r] = sc * (b_ih[row] + b_hh[row]);
        }
    const f32x4 chi = {(q == 0) ? b_lin[0] : 0.0f, 0.0f, 0.0f, 0.0f};

    const float* xb = x + b * SLEN;
    float*       ob = out + b * SLEN;

    // ---- state: c of units 5q..5q+4 (f32); h lives packed in bf (f16) ----
    float cc[5] = {0.0f, 0.0f, 0.0f, 0.0f, 0.0f};
    f16x8 bf;
#pragma unroll
    for (int s = 0; s < 8; ++s) bf[s] = (_Float16)0.0f;   // h(-1) = 0

    auto STEP = [&](float xt) -> float {
        f32x4 C[5];
#pragma unroll
        for (int m = 0; m < 5; ++m) {
            f32x4 ci;
#pragma unroll
            for (int r = 0; r < 4; ++r) ci[r] = fmaf(xt, xw[m][r], bb[m][r]);
            C[m] = __builtin_amdgcn_mfma_f32_16x16x32_f16(am[m], bf, ci, 0, 0, 0);
        }
#pragma unroll
        for (int m = 0; m < 5; ++m) {
            const float eI = fexp2(C[m][0]);
            const float eF = fexp2(C[m][1]);
            const float eG = fexp2(C[m][2]);
            const float eO = fexp2(C[m][3]);
            const float pF = 1.0f + eF;
            const float P  = (1.0f + eI) * (1.0f + eG);
            const float num = fmaf(cc[m], P, (1.0f - eG) * pF);
            cc[m] = fmaxf(num * frcp(pF * P), -34.0f);
            const float eC = fexp2(s2 * cc[m]);
            const float hv = (1.0f - eC) * frcp((1.0f + eO) * (1.0f + eC));
            bf[m] = (_Float16)hv;          // h(t), f16 RTN (same as R6b)
        }
        // head on the NEW h: y(t) = W_lin.h(t) + b_lin (skew fixed)
        const f32x4 Ch = __builtin_amdgcn_mfma_f32_16x16x32_f16(ah, bf, chi, 0, 0, 0);
        return Ch[0];                      // valid in lanes 0..15 (row 0)
    };

    // x double-buffer: 8 floats per body, loads issued a full body ahead
    f32x4 xA0 = *(const f32x4*)(xb);
    f32x4 xA1 = *(const f32x4*)(xb + 4);
    f32x4 xB0, xB1;

#pragma unroll 1
    for (int TP = 0; TP < SLEN; TP += 16) {
        // prefetch body B's x (consumed 8 steps later)
        xB0 = *(const f32x4*)(xb + TP + 8);
        xB1 = *(const f32x4*)(xb + TP + 12);

        f32x4 y0, y1;
        // ---- body A: steps TP .. TP+7 ----
        y0[0] = STEP(xA0[0]); y0[1] = STEP(xA0[1]);
        y0[2] = STEP(xA0[2]); y0[3] = STEP(xA0[3]);
        y1[0] = STEP(xA1[0]); y1[1] = STEP(xA1[1]);
        y1[2] = STEP(xA1[2]); y1[3] = STEP(xA1[3]);
        if (lane < 16) {
            *(f32x4*)(ob + TP)     = y0;
            *(f32x4*)(ob + TP + 4) = y1;
        }

        // prefetch next pair's x (wraps harmlessly on the last iteration)
        const int TN = (TP + 16) & (SLEN - 1);
        xA0 = *(const f32x4*)(xb + TN);
        xA1 = *(const f32x4*)(xb + TN + 4);

        // ---- body B: steps TP+8 .. TP+15 ----
        y0[0] = STEP(xB0[0]); y0[1] = STEP(xB0[1]);
        y0[2] = STEP(xB0[2]); y0[3] = STEP(xB0[3]);
        y1[0] = STEP(xB1[0]); y1[1] = STEP(xB1[1]);
        y1[2] = STEP(xB1[2]); y1[3] = STEP(xB1[3]);
        if (lane < 16) {
            *(f32x4*)(ob + TP + 8)  = y0;
            *(f32x4*)(ob + TP + 12) = y1;
        }
    }
}

extern "C" void kernel_launch(void* const* d_in, const int* in_sizes, int n_in,
                              void* d_out, int out_size, void* d_ws, size_t ws_size,
                              hipStream_t stream) {
    const float* x     = (const float*)d_in[0];
    const float* W_ih  = (const float*)d_in[1];
    const float* W_hh  = (const float*)d_in[2];
    const float* b_ih  = (const float*)d_in[3];
    const float* b_hh  = (const float*)d_in[4];
    const float* W_lin = (const float*)d_in[5];
    const float* b_lin = (const float*)d_in[6];
    float* out = (float*)d_out;

    const int nblocks = BATCH / 16;   // 256 blocks: 16 chains per wave, 1/CU
    lstm_fused<<<nblocks, 64, 0, stream>>>(x, W_ih, W_hh, b_ih, b_hh,
                                           W_lin, b_lin, out);
}

// Round 13
// 245.264 us; speedup vs baseline: 1.1253x; 1.1253x over previous
//
#include <hip/hip_runtime.h>

// LSTM B=4096, S=512, INPUT=1, HIDDEN=20 + linear head.
// R12: R6b structure (2048 single-wave blocks x 2 chains, 2 waves/SIMD, fp16
// LDS h-ring) with gate dots forced to v_pk_fma_f16 via INLINE ASM.
// Cost model (fits R3..R11 within a few %):
//   wall/SIMD-step = VALU issue + trans issue (NOT in VALUBusy, ~16cyc/op)
//   R6b:  647 VALU + 224 trans = 871 (meas. 886)  -> VALU-bound, dots=400.
//   R11b MFMA: 197+23 issue + 560 trans = 780 + latency (meas. 1003): the
//   16-chain wave piles all trans on ONE SIMD; 256-wave residency caps it.
// R9 tried pk_fma via C++ h2 operators: VALU went UP (712) -> compiler
// scalarized to v_fma_f16 pairs + repacks.  R12 emits the packed ops
// directly: per wave-step 40 pk (80cyc) + 8 fdot2 finish (40) + 4 fmaf (8)
// replaces 40 dot2 (200) + 4 fmaf.  Numerics identical to R9 (passed,
// absmax 9.77e-4): 5+5 split f16 pair-accumulators, exact fdot2((1,1))
// horizontal finish in f32.
// Kept: fused-reciprocal activations (5 exp2 + 2 rcp per unit):
//   c' = (c*(1+I)(1+G) + (1-G)(1+F)) * rcp((1+F)(1+I)(1+G))
//   h  = (1-C) * rcp((1+O)(1+C)),  C = exp2(-2*log2e*c'),  c clamped >= -34,
// deferred head per 16-step chunk (16 lanes/chain, coalesced store).

#define BATCH 4096
#define SLEN  512
#define H     20
#define CHUNK 16
#define LOG2E 1.44269504088896340736f
#define GSTRIDE 200   // words per group LDS region (16 rows * 12 + 8 pad)
#define RSTRIDE 12    // words per h row (10 half2 used + 2 pad)

typedef _Float16 h2 __attribute__((ext_vector_type(2)));

__device__ __forceinline__ float fexp2(float x) { return __builtin_amdgcn_exp2f(x); }
__device__ __forceinline__ float frcp(float x)  { return __builtin_amdgcn_rcpf(x); }
__device__ __forceinline__ h2 bch2(unsigned int u) { return __builtin_bit_cast(h2, u); }

// forced VOP3P packed f16 ops (R9's C++ operators got scalarized)
__device__ __forceinline__ h2 pkmul(h2 a, h2 b) {
    h2 d;
    asm("v_pk_mul_f16 %0, %1, %2" : "=v"(d) : "v"(a), "v"(b));
    return d;
}
__device__ __forceinline__ h2 pkfma(h2 a, h2 b, h2 c) {
    h2 d;
    asm("v_pk_fma_f16 %0, %1, %2, %3" : "=v"(d) : "v"(a), "v"(b), "v"(c));
    return d;
}

__global__ __launch_bounds__(64, 2) void lstm_fused(
    const float* __restrict__ x,      // [B, S, 1]
    const float* __restrict__ W_ih,   // [80, 1]
    const float* __restrict__ W_hh,   // [80, 20]
    const float* __restrict__ b_ih,   // [80]
    const float* __restrict__ b_hh,   // [80]
    const float* __restrict__ W_lin,  // [1, 20]
    const float* __restrict__ b_lin,  // [1]
    float* __restrict__ out)          // [B, S, 1]
{
    __shared__ __align__(16) unsigned int hw[3 * GSTRIDE];  // h ring, fp16 (grp2 = scratch)
    __shared__ float xbuf[3][CHUNK];
    _Float16* hh = (_Float16*)hw;

    const int lane = threadIdx.x;       // 0..63
    int grp = lane / H;                 // 0,1 real chains
    if (grp > 2) grp = 2;               // lanes 40..63 all dummy group 2
    const int j    = lane - grp * H;    // 0..19 real; 0..23 for dummy grp
    const bool valid = (grp < 2);
    const long b  = (long)blockIdx.x * 2 + grp;   // 2048*2 = 4096 exact
    const long bc = valid ? b : 0;                // dummies chew on chain 0's x

    const float s1 = -LOG2E;          // sigmoid pre-scale
    const float s2 = -2.0f * LOG2E;   // tanh pre-scale

    // ---- per-lane weights: 4 gate rows x 10 half2 (40 VGPRs), pre-scaled ----
    const int ju = (j < H) ? j : 0;   // clamp dummy lanes' row index (weights only)
    h2 w2[4][10];
    float bb[4], xw[4];
#pragma unroll
    for (int g = 0; g < 4; ++g) {
        const int row = g * H + ju;
        const float sc = (g == 2) ? s2 : s1;   // torch gate order i,f,g,o
#pragma unroll
        for (int k = 0; k < 10; ++k) {
            h2 t;
            t.x = (_Float16)(sc * W_hh[row * H + 2 * k]);
            t.y = (_Float16)(sc * W_hh[row * H + 2 * k + 1]);
            w2[g][k] = t;
        }
        bb[g] = sc * (b_ih[row] + b_hh[row]);
        xw[g] = sc * W_ih[row];
    }
    h2 wl2[10];
#pragma unroll
    for (int k = 0; k < 10; ++k) {
        h2 t;
        t.x = (_Float16)W_lin[2 * k];
        t.y = (_Float16)W_lin[2 * k + 1];
        wl2[k] = t;
    }
    const float blin = b_lin[0];
    h2 one2; one2.x = (_Float16)1.0f; one2.y = (_Float16)1.0f;

    const float* xb = x + bc * SLEN;
    float*       ob = out + bc * SLEN;

    const int gbase = grp * GSTRIDE;   // word bases 0,200,400 -> bank quads 0/8/16
    // h(-1) = 0 in ring row CHUNK-1 (dummy lanes spread across scratch row)
    hh[2 * (gbase + (CHUNK - 1) * RSTRIDE) + j] = (_Float16)0.0f;
    float c = 0.0f;

#pragma unroll 1
    for (int T = 0; T < SLEN; T += CHUNK) {
        if (j < CHUNK) xbuf[grp][j] = xb[T + j];   // coalesced x chunk -> LDS

#pragma unroll
        for (int i = 0; i < CHUNK; ++i) {
            const int rp = (i + CHUNK - 1) & (CHUNK - 1);
            const int base = gbase + rp * RSTRIDE;
            const float xt = xbuf[grp][i];          // group broadcast read
            // h(t-1) row: 20 fp16 = words 0..9 -> b128 + b128 + b64
            const uint4 A = *(const uint4*)&hw[base];
            const uint4 B = *(const uint4*)&hw[base + 4];
            const uint2 C2 = *(const uint2*)&hw[base + 8];
            const unsigned int pw[10] = {A.x, A.y, A.z, A.w,
                                         B.x, B.y, B.z, B.w, C2.x, C2.y};

            // ---- gates: forced v_pk_fma_f16, two 5-deep halves per gate ----
            h2 acc_a[4], acc_b[4];
#pragma unroll
            for (int g = 0; g < 4; ++g) {
                acc_a[g] = pkmul(bch2(pw[0]), w2[g][0]);
                acc_b[g] = pkmul(bch2(pw[5]), w2[g][5]);
            }
#pragma unroll
            for (int k = 1; k < 5; ++k)
#pragma unroll
                for (int g = 0; g < 4; ++g) {
                    acc_a[g] = pkfma(bch2(pw[k]),     w2[g][k],     acc_a[g]);
                    acc_b[g] = pkfma(bch2(pw[k + 5]), w2[g][k + 5], acc_b[g]);
                }
            float a[4];
#pragma unroll
            for (int g = 0; g < 4; ++g) {
                const float init = fmaf(xt, xw[g], bb[g]);
                // exact horizontal sums: x1.0 products, f32 accumulate
                const float t0 = __builtin_amdgcn_fdot2(acc_b[g], one2, init, false);
                a[g] = __builtin_amdgcn_fdot2(acc_a[g], one2, t0, false);
            }

            // ---- fused-reciprocal activations: 5 exp2 + 2 rcp ----
            const float eI = fexp2(a[0]);
            const float eF = fexp2(a[1]);
            const float eG = fexp2(a[2]);
            const float eO = fexp2(a[3]);
            const float pF = 1.0f + eF;
            const float P  = (1.0f + eI) * (1.0f + eG);
            const float num = fmaf(c, P, (1.0f - eG) * pF);
            c = fmaxf(num * frcp(pF * P), -34.0f);
            const float eC = fexp2(s2 * c);
            const float hval = (1.0f - eC) * frcp((1.0f + eO) * (1.0f + eC));
            // ring write: real lanes 0..19; dummy lanes spread over 0..23
            hh[2 * (gbase + i * RSTRIDE) + j] = (_Float16)hval;  // ds_write_b16
        }

        // ---- deferred head: lanes j<16 reduce one stored row each ----
        if (j < CHUNK) {
            const int rb = gbase + j * RSTRIDE;
            const uint4 A = *(const uint4*)&hw[rb];
            const uint4 B = *(const uint4*)&hw[rb + 4];
            const uint2 C2 = *(const uint2*)&hw[rb + 8];
            const unsigned int pwh[10] = {A.x, A.y, A.z, A.w,
                                          B.x, B.y, B.z, B.w, C2.x, C2.y};
            float y = blin;
#pragma unroll
            for (int k = 0; k < 10; ++k)
                y = __builtin_amdgcn_fdot2(bch2(pwh[k]), wl2[k], y, false);
            if (valid) ob[T + j] = y;   // coalesced 16-float burst per chain
        }
    }
}

extern "C" void kernel_launch(void* const* d_in, const int* in_sizes, int n_in,
                              void* d_out, int out_size, void* d_ws, size_t ws_size,
                              hipStream_t stream) {
    const float* x     = (const float*)d_in[0];
    const float* W_ih  = (const float*)d_in[1];
    const float* W_hh  = (const float*)d_in[2];
    const float* b_ih  = (const float*)d_in[3];
    const float* b_hh  = (const float*)d_in[4];
    const float* W_lin = (const float*)d_in[5];
    const float* b_lin = (const float*)d_in[6];
    float* out = (float*)d_out;

    const int nblocks = BATCH / 2;   // 2048 single-wave blocks: 2 per SIMD
    lstm_fused<<<nblocks, 64, 0, stream>>>(x, W_ih, W_hh, b_ih, b_hh,
                                           W_lin, b_lin, out);
}

// Round 14
// 220.071 us; speedup vs baseline: 1.2541x; 1.1145x over previous
//
#include <hip/hip_runtime.h>

// LSTM B=4096, S=512, INPUT=1, HIDDEN=20 + linear head.
// R13: cooperative 4-wave block — one LSTM step split across the CU's 4
// SIMDs.  Session model (fits R3..R12): wall = max(L, issue); every
// single-wave structure has serial step latency L ~ 850-1000 cyc and
// chains (4096) are too few for >2 waves/SIMD, so L is never hidden.
// R12 pinned the rates: dot2 full-rate 2cyc (pk_fma swap RAISED issue),
// trans ~16 cyc/wave64.  R11b showed the MFMA path works numerically but
// put 16 chains' trans (560 cyc/step) + everything on ONE SIMD per CU.
// Here: block = 256 thr = 4 waves on one CU's 4 SIMDs, 16 chains/block,
// 256 blocks = full chip.  The 5 independent gate-MFMAs are split:
// wave0 m={0,1}, wave1 m={2}, wave2 m={3}, wave3 m={4}+head.  Per step:
// read full-h fragment from double-buffered LDS (b128, 2-way-bank-free)
// -> own mfma(s) + act (7-14 trans/wave vs 35) -> write own h slots ->
// __syncthreads.  Step ~ max(L'~390, issue~350) vs 886.
// Layout (verified in R11b, absmax 9.77e-4): A row 4Q+r = gate r of unit
// 5Q+m; k-slot s = unit 5q+s (s<5, slots 5-7 zero); C col=lane&15,
// row=4*(lane>>4)+reg; x*W_ih+bias via f32 C-operand.  h transport:
// hrow[parity][chain n][40 halfs], unit 5q+m at half 8q+m (write b16/b32,
// read b128 at half 8q; pad slots killed by A zeros; word (20n+4q)%32 ->
// only (n,n+8) 2-way aliasing = free).  Head: one-step skew off the
// just-read h(t-1) (R8 pattern), epilogue for t=511.
// Grid: 256 blocks x 256 threads.

#define BATCH 4096
#define SLEN  512
#define H     20
#define LOG2E 1.44269504088896340736f

typedef _Float16 f16x8 __attribute__((ext_vector_type(8)));
typedef _Float16 h2    __attribute__((ext_vector_type(2)));
typedef float    f32x4 __attribute__((ext_vector_type(4)));

__device__ __forceinline__ float fexp2(float x) { return __builtin_amdgcn_exp2f(x); }
__device__ __forceinline__ float frcp(float x)  { return __builtin_amdgcn_rcpf(x); }

// one unit's activations (R11b-verified): Cv = [i,f,g,o] pre-scaled pre-acts
#define ACT(Cv, CC, HV) {                                             \
    const float eI = fexp2((Cv)[0]);                                  \
    const float eF = fexp2((Cv)[1]);                                  \
    const float eG = fexp2((Cv)[2]);                                  \
    const float eO = fexp2((Cv)[3]);                                  \
    const float pF = 1.0f + eF;                                       \
    const float P  = (1.0f + eI) * (1.0f + eG);                       \
    const float num = fmaf(CC, P, (1.0f - eG) * pF);                  \
    CC = fmaxf(num * frcp(pF * P), -34.0f);                           \
    const float eC = fexp2(s2 * CC);                                  \
    HV = (1.0f - eC) * frcp((1.0f + eO) * (1.0f + eC));               \
}

__global__ __launch_bounds__(256, 1) void lstm_fused(
    const float* __restrict__ x,      // [B, S, 1]
    const float* __restrict__ W_ih,   // [80, 1]
    const float* __restrict__ W_hh,   // [80, 20]
    const float* __restrict__ b_ih,   // [80]
    const float* __restrict__ b_hh,   // [80]
    const float* __restrict__ W_lin,  // [1, 20]
    const float* __restrict__ b_lin,  // [1]
    float* __restrict__ out)          // [B, S, 1]
{
    // h transport: [parity][chain][40 halfs]; row stride 80B, 16B-aligned frags
    __shared__ __align__(16) _Float16 hrow[2][16][40];

    const int tid  = threadIdx.x;
    const int wv   = tid >> 6;          // wave 0..3
    const int lane = tid & 63;
    const int q    = lane >> 4;         // k-group / unit-block 0..3
    const int n    = lane & 15;         // chain column 0..15
    const long b   = (long)blockIdx.x * 16 + n;   // 256*16 = 4096 exact

    const float s1 = -LOG2E;            // sigmoid pre-scale
    const float s2 = -2.0f * LOG2E;     // tanh pre-scale

    // owned gate-mfmas: wv0:{0,1}  wv1:{2}  wv2:{3}  wv3:{4}+head
    const int  m0   = (wv == 0) ? 0 : (wv + 1);
    const bool dual = (wv == 0);

    // ---- A fragments (f16): row = n -> gate gA of unit uA+m; k-slot s =
    // unit 5q+s (s<5), slots 5-7 zero (kill B pad garbage). ----
    const int gA = n & 3;
    const int uA = (n >> 2) * 5;
    const float scA = (gA == 2) ? s2 : s1;   // torch gate order i,f,g,o
    f16x8 am0, am1;
    {
        const int r0 = gA * H + uA + m0;
        const int r1 = gA * H + uA + 1;      // m=1 (used only by wave 0)
#pragma unroll
        for (int s = 0; s < 8; ++s) {
            am0[s] = (_Float16)((s < 5) ? scA * W_hh[r0 * H + 5 * q + s] : 0.0f);
            am1[s] = (_Float16)((s < 5) ? scA * W_hh[r1 * H + 5 * q + s] : 0.0f);
        }
    }
    // head A (wave 3): row 0 = W_lin; b_lin via C-input (row 0 lives in q=0)
    f16x8 ah;
#pragma unroll
    for (int s = 0; s < 8; ++s)
        ah[s] = (_Float16)((n == 0 && s < 5) ? W_lin[5 * q + s] : 0.0f);
    const f32x4 chi = {(q == 0) ? b_lin[0] : 0.0f, 0.0f, 0.0f, 0.0f};

    // ---- f32 C-init constants for owned units: C pos (reg r) = gate r of
    // unit 5q+m, chain n -> sc_r*(x_n*W_ih + b_ih + b_hh) ----
    f32x4 xw0, bb0, xw1, bb1;
#pragma unroll
    for (int r = 0; r < 4; ++r) {
        const float sc = (r == 2) ? s2 : s1;
        const int r0 = r * H + 5 * q + m0;
        const int r1 = r * H + 5 * q + 1;
        xw0[r] = sc * W_ih[r0];  bb0[r] = sc * (b_ih[r0] + b_hh[r0]);
        xw1[r] = sc * W_ih[r1];  bb1[r] = sc * (b_ih[r1] + b_hh[r1]);
    }

    const float* xb = x + b * SLEN;
    float*       ob = out + b * SLEN;

    // zero both h buffers (h(-1)=0 lives in parity 1)
    for (int i = tid; i < 640; i += 256) ((unsigned*)hrow)[i] = 0u;
    __syncthreads();

    float cc0 = 0.0f, cc1 = 0.0f;   // c state of owned units
    f32x4 ya;                       // wave3: y quad (one-step skew)
    f32x4 xc = *(const f32x4*)xb;   // current x quad

#define STEP(p)                                                            \
    {                                                                      \
        const f16x8 bf = *(const f16x8*)&hrow[((p) & 1) ^ 1][n][8 * q];    \
        if (wv == 3) {                                                     \
            const f32x4 Ch =                                               \
                __builtin_amdgcn_mfma_f32_16x16x32_f16(ah, bf, chi, 0, 0, 0); \
            const float yv = Ch[0];            /* y(t-1), t = 4k+p */      \
            if ((p) == 0) {                                                \
                ya[3] = yv;                                                \
                if (k > 0 && lane < 16) *(f32x4*)(ob + 4 * k - 4) = ya;    \
            } else if ((p) == 1) ya[0] = yv;                               \
            else if ((p) == 2) ya[1] = yv;                                 \
            else ya[2] = yv;                                               \
        }                                                                  \
        const float xt = xc[(p)];                                          \
        f32x4 ci0;                                                         \
        ci0[0] = fmaf(xt, xw0[0], bb0[0]);                                 \
        ci0[1] = fmaf(xt, xw0[1], bb0[1]);                                 \
        ci0[2] = fmaf(xt, xw0[2], bb0[2]);                                 \
        ci0[3] = fmaf(xt, xw0[3], bb0[3]);                                 \
        f32x4 C0 = __builtin_amdgcn_mfma_f32_16x16x32_f16(am0, bf, ci0, 0, 0, 0); \
        float h0v;                                                         \
        ACT(C0, cc0, h0v);                                                 \
        if (dual) {                                                        \
            f32x4 ci1;                                                     \
            ci1[0] = fmaf(xt, xw1[0], bb1[0]);                             \
            ci1[1] = fmaf(xt, xw1[1], bb1[1]);                             \
            ci1[2] = fmaf(xt, xw1[2], bb1[2]);                             \
            ci1[3] = fmaf(xt, xw1[3], bb1[3]);                             \
            f32x4 C1 = __builtin_amdgcn_mfma_f32_16x16x32_f16(am1, bf, ci1, 0, 0, 0); \
            float h1v;                                                     \
            ACT(C1, cc1, h1v);                                             \
            h2 pr; pr.x = (_Float16)h0v; pr.y = (_Float16)h1v;             \
            *(h2*)&hrow[(p) & 1][n][8 * q] = pr;     /* units m=0,1 */     \
        } else {                                                           \
            hrow[(p) & 1][n][8 * q + m0] = (_Float16)h0v;                  \
        }                                                                  \
        __syncthreads();                                                   \
    }

#pragma unroll 1
    for (int k = 0; k < 128; ++k) {
        const int t0 = 4 * k;
        const int tn = (t0 + 4 < SLEN) ? t0 + 4 : SLEN - 4;   // clamp
        const f32x4 xn = *(const f32x4*)(xb + tn);            // prefetch

        STEP(0) STEP(1) STEP(2) STEP(3)

        xc = xn;
    }
#undef STEP

    // epilogue: y(511) from h(511) (parity 1, published by last barrier)
    if (wv == 3) {
        const f16x8 bf = *(const f16x8*)&hrow[1][n][8 * q];
        const f32x4 Ch = __builtin_amdgcn_mfma_f32_16x16x32_f16(ah, bf, chi, 0, 0, 0);
        ya[3] = Ch[0];
        if (lane < 16) *(f32x4*)(ob + SLEN - 4) = ya;
    }
}

extern "C" void kernel_launch(void* const* d_in, const int* in_sizes, int n_in,
                              void* d_out, int out_size, void* d_ws, size_t ws_size,
                              hipStream_t stream) {
    const float* x     = (const float*)d_in[0];
    const float* W_ih  = (const float*)d_in[1];
    const float* W_hh  = (const float*)d_in[2];
    const float* b_ih  = (const float*)d_in[3];
    const float* b_hh  = (const float*)d_in[4];
    const float* W_lin = (const float*)d_in[5];
    const float* b_lin = (const float*)d_in[6];
    float* out = (float*)d_out;

    const int nblocks = BATCH / 16;   // 256 blocks x 4 waves: full chip
    lstm_fused<<<nblocks, 256, 0, stream>>>(x, W_ih, W_hh, b_ih, b_hh,
                                            W_lin, b_lin, out);
}